// Round 13
// baseline (257.209 us; speedup 1.0000x reference)
//
#include <hip/hip_runtime.h>
#include <cmath>

#define NB 16
#define MM 4096
#define MP1 4097
#define DD 512
#define LSEQ 196
#define RWS 32              // rows per block
#define NRB 129             // ceil(4097/32)
#define MARGIN 0.05f
#define CANDMAX 128

typedef float f32x4 __attribute__((ext_vector_type(4)));
typedef short bf16x8 __attribute__((ext_vector_type(8)));
typedef unsigned short u16x8 __attribute__((ext_vector_type(8)));

static __device__ __forceinline__ unsigned short bf16_rne(float x) {
  union { float f; unsigned u; } c; c.f = x;
  unsigned u = c.u;
  u += 0x7fffu + ((u >> 16) & 1u);
  return (unsigned short)(u >> 16);
}
static __device__ __forceinline__ float bf16_to_f(unsigned short h) {
  union { unsigned u; float f; } c; c.u = ((unsigned)h) << 16;
  return c.f;
}
static __device__ __forceinline__ unsigned cvt_pk_bf16(float lo, float hi) {
  unsigned r;
  asm("v_cvt_pk_bf16_f32 %0, %1, %2" : "=v"(r) : "v"(lo), "v"(hi));
  return r;
}
static __device__ __forceinline__ float sig_prec(float v) { return 1.0f / (1.0f + expf(-v)); }
static __device__ __forceinline__ float sig_fast(float v) { return 1.0f / (1.0f + __expf(-v)); }
static __device__ __forceinline__ float tanh_fast(float v) { return fmaf(2.0f, sig_fast(2.0f * v), -1.0f); }

// ---- pack Wv,Wu hi-bf16, col-group-interleaved MFMA frag order -------------
// slot ctg2 = 2*ctg + mat (mat 0=Wv 1=Wu); addr = (ctg2*16 + ksg)*512 + l*8
__global__ __launch_bounds__(256) void k_packW(const float* __restrict__ Wv,
                                               const float* __restrict__ Wu,
                                               unsigned short* __restrict__ Bc) {
  const int gid = blockIdx.x * 256 + threadIdx.x;  // 65536
  const int l = gid & 63;
  const int ksg = (gid >> 6) & 15;
  const int ctg = (gid >> 10) & 31;
  const int mat = gid >> 15;
  const float* W = mat ? Wu : Wv;
  const int col = ctg * 16 + (l & 15);
  const int kb = ksg * 32 + (l >> 4) * 8;
  u16x8 hi;
#pragma unroll
  for (int i = 0; i < 8; ++i) hi[i] = bf16_rne(W[(size_t)(kb + i) * DD + col]);
  const int ctg2 = ctg * 2 + mat;
  *(u16x8*)(Bc + ((size_t)(ctg2 * 16 + ksg)) * 512 + l * 8) = hi;
}

// ---- fused: logits for 32 rows over ALL 1024 ccols + in-block z partial ----
// 512 thr (8 waves). Two sequential slot-halves h=0,1: per half, wave w owns
// slots h*32 + w*4 + [0,4) (= col-groups h*16 + w*2 + {0,1}, v&u pairs).
// acc[2][4] = 32 AGPR per half (re-zeroed); prow accumulates across halves.
// Total regs/wave = ~96 arch + 32 AGPR <= 128 -> 4 waves/SIMD -> 2 blocks/CU
// co-resident (stage/epilogue/z of one block overlaps MFMA of the other).
// A-tile 32KB LDS, R10/R12-verified XOR swizzle (conflict-free all 3 accesses).
__global__ __launch_bounds__(512, 4) void k_scores(
    const float* __restrict__ x, const float* __restrict__ feat_mem,
    const unsigned short* __restrict__ Bc,
    const float* __restrict__ bv, const float* __restrict__ bu,
    const float* __restrict__ Ww, const float* __restrict__ bw,
    float* __restrict__ logits, float* __restrict__ zacc) {
  const int rb = blockIdx.x, b = blockIdx.y;
  const int row0 = rb * RWS;
  const int tid = threadIdx.x, wave = tid >> 6, l = tid & 63;

  __shared__ __align__(16) unsigned short A[32 * 512];  // 32 KB, frag (ksg*2+rt)*512
  __shared__ float sred[8][RWS];
  __shared__ float sscore[RWS];

  // ---- stage: coalesced row-major fp32 load -> cvt -> swizzled ds_write ----
  {
    const int r = tid >> 4;       // 0..31
    const int j = tid & 15;
    const int grow = row0 + r;
    const float* srcrow = nullptr;
    if (grow < MM) srcrow = feat_mem + ((size_t)b * MM + grow) * DD;
    else if (grow == MM) srcrow = x + (size_t)b * LSEQ * DD;
    const int rt = r >> 4, lrow = r & 15;
#pragma unroll
    for (int it = 0; it < 8; ++it) {
      const int k0 = it * 64 + j * 4;
      const float4 v = srcrow ? *(const float4*)(srcrow + k0) : make_float4(0.f, 0.f, 0.f, 0.f);
      const int ksg = k0 >> 5, lhi = (k0 >> 3) & 3, ii = k0 & 7;  // ii in {0,4}
      uint2 p;
      p.x = cvt_pk_bf16(v.x, v.y);
      p.y = cvt_pk_bf16(v.z, v.w);
      const int U = (ksg * 2 + rt) * 512 + lhi * 128 +
                    ((lrow * 8) ^ (lhi << 3) ^ ((ksg & 1) << 5)) + ii;
      *(uint2*)(A + U) = p;
    }
  }
  __syncthreads();

  // ---- MFMA: 2 halves x 16 ksg x (2 rt x 4 ct); B reg-double-buffered ------
  const int lanebase = l * 8 ^ ((l >> 4) << 3);
  float prow[2][4];
#pragma unroll
  for (int i = 0; i < 2; ++i)
#pragma unroll
    for (int j2 = 0; j2 < 4; ++j2) prow[i][j2] = 0.f;

#pragma unroll
  for (int h = 0; h < 2; ++h) {
    f32x4 acc[2][4];
#pragma unroll
    for (int i = 0; i < 2; ++i)
#pragma unroll
      for (int j2 = 0; j2 < 4; ++j2) acc[i][j2] = (f32x4){0.f, 0.f, 0.f, 0.f};

    const unsigned short* Bwave = Bc + ((size_t)((h * 32 + wave * 4) * 16)) * 512 + l * 8;
    bf16x8 bbA[4], bbB[4];

#define BLOAD(dst, ksg)                                                     \
    {                                                                       \
      _Pragma("unroll")                                                     \
      for (int ct = 0; ct < 4; ++ct)                                        \
        dst[ct] = *(const bf16x8*)(Bwave + (size_t)(ct * 16 + (ksg)) * 512);\
    }
#define KSTEP(CUR, NXT, ksg, last)                                                        \
    {                                                                                     \
      if (!(last)) BLOAD(NXT, (ksg) + 1);                                                 \
      const unsigned short* Ab = A + (ksg) * 1024 + (lanebase ^ (((ksg) & 1) << 5));      \
      const bf16x8 hiA0 = *(const bf16x8*)(Ab);                                           \
      const bf16x8 hiA1 = *(const bf16x8*)(Ab + 512);                                     \
      _Pragma("unroll")                                                                   \
      for (int ct = 0; ct < 4; ++ct) {                                                    \
        acc[0][ct] = __builtin_amdgcn_mfma_f32_16x16x32_bf16(hiA0, CUR[ct], acc[0][ct], 0, 0, 0); \
        acc[1][ct] = __builtin_amdgcn_mfma_f32_16x16x32_bf16(hiA1, CUR[ct], acc[1][ct], 0, 0, 0); \
      }                                                                                   \
    }

    BLOAD(bbA, 0);
#pragma unroll
    for (int kk = 0; kk < 8; ++kk) {
      KSTEP(bbA, bbB, 2 * kk, false);
      KSTEP(bbB, bbA, 2 * kk + 1, (kk == 7));
    }
#undef BLOAD
#undef KSTEP

    // partial epilogue for this half's 32 cols (2 col-groups)
#pragma unroll
    for (int gp = 0; gp < 2; ++gp) {
      const int col = (h * 16 + wave * 2 + gp) * 16 + (l & 15);
      const float bvc = bv[col], buc = bu[col], wwc = Ww[col];
#pragma unroll
      for (int rt = 0; rt < 2; ++rt)
#pragma unroll
        for (int rr = 0; rr < 4; ++rr) {
          const float vv = tanh_fast(acc[rt][2 * gp][rr] + bvc);
          const float uu = sig_fast(acc[rt][2 * gp + 1][rr] + buc);
          prow[rt][rr] = fmaf(vv * uu, wwc, prow[rt][rr]);
        }
    }
  }

  // ---- reduce prow over lanes' 16-col groups, then over waves --------------
#pragma unroll
  for (int off = 1; off < 16; off <<= 1)
#pragma unroll
    for (int rt = 0; rt < 2; ++rt)
#pragma unroll
      for (int rr = 0; rr < 4; ++rr) prow[rt][rr] += __shfl_xor(prow[rt][rr], off, 64);

  if ((l & 15) == 0) {
#pragma unroll
    for (int rt = 0; rt < 2; ++rt)
#pragma unroll
      for (int rr = 0; rr < 4; ++rr) sred[wave][rt * 16 + (l >> 4) * 4 + rr] = prow[rt][rr];
  }
  __syncthreads();

  if (tid < RWS) {
    float s = 0.f;
#pragma unroll
    for (int w = 0; w < 8; ++w) s += sred[w][tid];
    const int row = row0 + tid;
    if (row < MP1) logits[(size_t)b * MP1 + row] = s;   // raw logit (no bw)
    sscore[tid] = sig_fast(s + bw[0]);
  }
  __syncthreads();

  // ---- in-block z partial: zacc[d] += sum_r score[r] * A[r][d] (swizzled) --
  {
    const int d = tid;  // 0..511
    const int ksg = d >> 5, lhi = (d >> 3) & 3, ii = d & 7;
    const int ubase = ksg * 1024 + lhi * 128 + ii;
    const int swz = (lhi << 3) ^ ((ksg & 1) << 5);
    float zp = 0.f;
#pragma unroll
    for (int r = 0; r < RWS; ++r) {
      const int U = ubase + (r >> 4) * 512 + (((r & 15) * 8) ^ swz);
      zp = fmaf(sscore[r], bf16_to_f(A[U]), zp);
    }
    atomicAdd(&zacc[(size_t)b * DD + d], zp);
  }
}

// ---- candidate selection: rows with cheap logit <= min + MARGIN ------------
__global__ __launch_bounds__(256) void k_cand(const float* __restrict__ logits,
                                              int* __restrict__ cand,
                                              int* __restrict__ cnt) {
  const int b = blockIdx.x, tid = threadIdx.x;
  __shared__ float sv[256];
  __shared__ int scnt;
  float m = INFINITY;
  for (int i = tid; i < MP1; i += 256) m = fminf(m, logits[(size_t)b * MP1 + i]);
  sv[tid] = m;
  __syncthreads();
  for (int s = 128; s >= 1; s >>= 1) {
    if (tid < s) sv[tid] = fminf(sv[tid], sv[tid + s]);
    __syncthreads();
  }
  const float minv = sv[0];
  if (tid == 0) scnt = 0;
  __syncthreads();
  for (int i = tid; i < MP1; i += 256) {
    if (logits[(size_t)b * MP1 + i] <= minv + MARGIN) {
      const int p = atomicAdd(&scnt, 1);
      if (p < CANDMAX) cand[b * CANDMAX + p] = i;
    }
  }
  __syncthreads();
  if (tid == 0) cnt[b] = (scnt < CANDMAX) ? scnt : CANDMAX;
}

// ---- exact fp32 logit partials for candidate rows (col-block parallel) -----
__global__ __launch_bounds__(256) void k_refine(
    const float* __restrict__ x, const float* __restrict__ feat_mem,
    const float* __restrict__ Wv, const float* __restrict__ bv,
    const float* __restrict__ Wu, const float* __restrict__ bu,
    const float* __restrict__ Ww,
    const int* __restrict__ cand, const int* __restrict__ cnt,
    float* __restrict__ candpart) {
  const int b = blockIdx.z, c = blockIdx.y, cb = blockIdx.x;
  if (c >= cnt[b]) return;
  const int row = cand[b * CANDMAX + c];
  const int tid = threadIdx.x;
  const int jl = tid & 63;
  const int ks = tid >> 6;
  const int col = cb * 64 + jl;
  __shared__ __align__(16) float sfeat[DD];
  __shared__ float sredv[4][64];
  __shared__ float sredu[4][64];
  const float* src = (row < MM) ? feat_mem + ((size_t)b * MM + row) * DD
                                : x + (size_t)b * LSEQ * DD;
  if (tid < 128) ((float4*)sfeat)[tid] = ((const float4*)src)[tid];
  __syncthreads();
  float v = 0.f, u = 0.f;
  const float* wvp = Wv + (size_t)(ks * 128) * DD + col;
  const float* wup = Wu + (size_t)(ks * 128) * DD + col;
#pragma unroll 8
  for (int k = 0; k < 128; ++k) {
    const float a = sfeat[ks * 128 + k];
    v = fmaf(a, wvp[(size_t)k * DD], v);
    u = fmaf(a, wup[(size_t)k * DD], u);
  }
  sredv[ks][jl] = v;
  sredu[ks][jl] = u;
  __syncthreads();
  if (tid < 64) {
    const float vv = (sredv[0][jl] + sredv[1][jl]) + (sredv[2][jl] + sredv[3][jl]);
    const float uu = (sredu[0][jl] + sredu[1][jl]) + (sredu[2][jl] + sredu[3][jl]);
    float g = tanhf(vv + bv[col]) * sig_prec(uu + bu[col]) * Ww[col];
#pragma unroll
    for (int off = 1; off < 64; off <<= 1) g += __shfl_xor(g, off, 64);
    if (jl == 0) candpart[((size_t)b * CANDMAX + c) * 8 + cb] = g;
  }
}

// ---- finalize: argmin over refined candidate logits + exact-rational argmax -
__global__ __launch_bounds__(256) void k_finalize2(
    const int* __restrict__ cand, const float* __restrict__ candpart,
    const int* __restrict__ cnt, const int* __restrict__ freq_mem,
    const int* __restrict__ min_mem, const float* __restrict__ zacc,
    float* __restrict__ out_z, float* __restrict__ out_freq,
    float* __restrict__ out_min, int* __restrict__ rm_attn) {
  const int b = blockIdx.x, tid = threadIdx.x;
  __shared__ float sv[256];
  __shared__ int si[256];
  __shared__ int sn[256], sd[256], sj[256];
  __shared__ int s_attn, s_rm;

  const int n = cnt[b];
  float v = INFINITY;
  int idx = MP1;
  if (tid < n) {
    const float* p = candpart + ((size_t)b * CANDMAX + tid) * 8;
    v = ((p[0] + p[1]) + (p[2] + p[3])) + ((p[4] + p[5]) + (p[6] + p[7]));
    idx = cand[b * CANDMAX + tid];
  }
  sv[tid] = v; si[tid] = idx;
  __syncthreads();
  for (int s = 128; s >= 1; s >>= 1) {
    if (tid < s) {
      const float v2 = sv[tid + s]; const int i2 = si[tid + s];
      if (v2 < sv[tid] || (v2 == sv[tid] && i2 < si[tid])) { sv[tid] = v2; si[tid] = i2; }
    }
    __syncthreads();
  }
  if (tid == 0) s_attn = si[0];
  __syncthreads();
  const int attn = s_attn;

  int bn = -1, bd = 1, bj = 0;
  for (int i = tid; i < MP1; i += 256) {
    int num, den;
    if (i < MM) {
      den = freq_mem[(size_t)b * MM + i] + 1;
      num = min_mem[(size_t)b * MM + i] + (i == attn ? 1 : 0);
      if (den <= 5) num = 0;
    } else { den = 1; num = 0; }
    if (num * bd > bn * den) { bn = num; bd = den; bj = i; }
  }
  sn[tid] = bn; sd[tid] = bd; sj[tid] = bj;
  __syncthreads();
  for (int s = 128; s >= 1; s >>= 1) {
    if (tid < s) {
      const int n2 = sn[tid + s], d2 = sd[tid + s], j2 = sj[tid + s];
      const int lft = n2 * sd[tid], rgt = sn[tid] * d2;
      if (lft > rgt || (lft == rgt && j2 < sj[tid])) { sn[tid] = n2; sd[tid] = d2; sj[tid] = j2; }
    }
    __syncthreads();
  }
  if (tid == 0) { s_rm = sj[0]; rm_attn[b * 2] = attn; rm_attn[b * 2 + 1] = sj[0]; }
  __syncthreads();
  const int rm = s_rm;

  for (int i = tid; i < MM; i += 256) {
    const int src = (i < rm) ? i : i + 1;
    int fv, mv;
    if (src < MM) {
      fv = freq_mem[(size_t)b * MM + src] + 1;
      mv = min_mem[(size_t)b * MM + src] + (src == attn ? 1 : 0);
    } else {
      fv = 1; mv = (attn == MM) ? 1 : 0;
    }
    out_freq[(size_t)b * MM + i] = (float)fv;
    out_min[(size_t)b * MM + i] = (float)mv;
  }
  for (int d = tid; d < DD; d += 256) out_z[(size_t)b * DD + d] = zacc[(size_t)b * DD + d];
}

// ---- feat_out gather (verified R1-R12) --------------------------------------
__global__ __launch_bounds__(256) void k_gather(
    const float* __restrict__ feat_mem, const float* __restrict__ x,
    const int* __restrict__ rm_attn, float* __restrict__ out_feat) {
  const int b = blockIdx.y;
  const int rm = rm_attn[b * 2 + 1];
  const int row = blockIdx.x * 4 + (threadIdx.x >> 6);
  const int lane = threadIdx.x & 63;
  const int src = (row < rm) ? row : row + 1;
  const float* sp = (src < MM) ? (feat_mem + ((size_t)b * MM + src) * DD)
                               : (x + (size_t)b * LSEQ * DD);
  float* dp = out_feat + ((size_t)b * MM + row) * DD;
  const float4 v0 = reinterpret_cast<const float4*>(sp)[lane];
  const float4 v1 = reinterpret_cast<const float4*>(sp)[lane + 64];
  reinterpret_cast<float4*>(dp)[lane] = v0;
  reinterpret_cast<float4*>(dp)[lane + 64] = v1;
}

extern "C" void kernel_launch(void* const* d_in, const int* in_sizes, int n_in,
                              void* d_out, int out_size, void* d_ws, size_t ws_size,
                              hipStream_t stream) {
  const float* x        = (const float*)d_in[0];
  const float* feat_mem = (const float*)d_in[1];
  const int*   freq_mem = (const int*)d_in[2];
  const int*   min_mem  = (const int*)d_in[3];
  const float* Wv       = (const float*)d_in[4];
  const float* bv       = (const float*)d_in[5];
  const float* Wu       = (const float*)d_in[6];
  const float* bu       = (const float*)d_in[7];
  const float* Ww       = (const float*)d_in[8];
  const float* bw       = (const float*)d_in[9];

  float* ws       = (float*)d_ws;
  float* logits   = ws;                                   // 65552
  float* zacc     = ws + NB * MP1;                        // 8192
  float* candpart = zacc + NB * DD;                       // 16384
  int*   cand     = (int*)(candpart + NB * CANDMAX * 8);  // 2048
  int*   cnt      = cand + NB * CANDMAX;                  // 16
  int*   rm_attn  = cnt + NB;                             // 32
  unsigned short* Bc = (unsigned short*)(rm_attn + 32);   // 1 MB

  float* out_z    = (float*)d_out;
  float* out_feat = out_z + NB * DD;
  float* out_freq = out_feat + (size_t)NB * MM * DD;
  float* out_min  = out_freq + (size_t)NB * MM;

  hipMemsetAsync(zacc, 0, NB * DD * sizeof(float), stream);
  hipMemsetAsync(cnt, 0, NB * sizeof(int), stream);

  k_packW<<<dim3(256), dim3(256), 0, stream>>>(Wv, Wu, Bc);
  k_scores<<<dim3(NRB, NB), dim3(512), 0, stream>>>(x, feat_mem, Bc, bv, bu, Ww, bw,
                                                    logits, zacc);
  k_cand<<<dim3(NB), dim3(256), 0, stream>>>(logits, cand, cnt);
  k_refine<<<dim3(8, CANDMAX, NB), dim3(256), 0, stream>>>(x, feat_mem, Wv, bv, Wu, bu, Ww,
                                                           cand, cnt, candpart);
  k_finalize2<<<dim3(NB), dim3(256), 0, stream>>>(cand, candpart, cnt, freq_mem, min_mem, zacc,
                                                  out_z, out_freq, out_min, rm_attn);
  k_gather<<<dim3(MM / 4, NB), dim3(256), 0, stream>>>(feat_mem, x, rm_attn, out_feat);
}

// Round 14
// 218.658 us; speedup vs baseline: 1.1763x; 1.1763x over previous
//
#include <hip/hip_runtime.h>
#include <cmath>

#define NB 16
#define MM 4096
#define MP1 4097
#define DD 512
#define LSEQ 196
#define NRB 65              // row-blocks of 64 rows
#define MARGIN 0.05f
#define CANDMAX 128

typedef float f32x4 __attribute__((ext_vector_type(4)));
typedef short bf16x8 __attribute__((ext_vector_type(8)));
typedef unsigned short u16x8 __attribute__((ext_vector_type(8)));

static __device__ __forceinline__ unsigned short bf16_rne(float x) {
  union { float f; unsigned u; } c; c.f = x;
  unsigned u = c.u;
  u += 0x7fffu + ((u >> 16) & 1u);
  return (unsigned short)(u >> 16);
}
static __device__ __forceinline__ float bf16_to_f(unsigned short h) {
  union { unsigned u; float f; } c; c.u = ((unsigned)h) << 16;
  return c.f;
}
static __device__ __forceinline__ unsigned cvt_pk_bf16(float lo, float hi) {
  unsigned r;
  asm("v_cvt_pk_bf16_f32 %0, %1, %2" : "=v"(r) : "v"(lo), "v"(hi));
  return r;
}
static __device__ __forceinline__ float sig_prec(float v) { return 1.0f / (1.0f + expf(-v)); }
static __device__ __forceinline__ float sig_fast(float v) { return 1.0f / (1.0f + __expf(-v)); }
static __device__ __forceinline__ float tanh_fast(float v) { return fmaf(2.0f, sig_fast(2.0f * v), -1.0f); }

// ---- pack Wv,Wu hi-bf16, col-group-interleaved MFMA frag order -------------
// slot ctg2 = 2*ctg + mat (mat 0=Wv 1=Wu); addr = (ctg2*16 + ksg)*512 + l*8
__global__ __launch_bounds__(256) void k_packW(const float* __restrict__ Wv,
                                               const float* __restrict__ Wu,
                                               unsigned short* __restrict__ Bc) {
  const int gid = blockIdx.x * 256 + threadIdx.x;  // 65536
  const int l = gid & 63;
  const int ksg = (gid >> 6) & 15;
  const int ctg = (gid >> 10) & 31;
  const int mat = gid >> 15;
  const float* W = mat ? Wu : Wv;
  const int col = ctg * 16 + (l & 15);
  const int kb = ksg * 32 + (l >> 4) * 8;
  u16x8 hi;
#pragma unroll
  for (int i = 0; i < 8; ++i) hi[i] = bf16_rne(W[(size_t)(kb + i) * DD + col]);
  const int ctg2 = ctg * 2 + mat;
  *(u16x8*)(Bc + ((size_t)(ctg2 * 16 + ksg)) * 512 + l * 8) = hi;
}

// ---- fused: logits for 64 rows over ALL cols + in-block z partial ----------
// R6 structure (16 waves, lazy in-loop B loads, no dbuf -> VGPR 64, no spill)
// + R8-verified XOR swizzle (lane-offset ^= (lhi<<3) ^ ((ks&1)<<5)) giving
// conflict-free stage-write / z-read; MFMA read is an in-fragment lane perm.
__global__ __launch_bounds__(1024) void k_scores(
    const float* __restrict__ x, const float* __restrict__ feat_mem,
    const unsigned short* __restrict__ Bc,
    const float* __restrict__ bv, const float* __restrict__ bu,
    const float* __restrict__ Ww, const float* __restrict__ bw,
    float* __restrict__ logits, float* __restrict__ zacc) {
  const int rb = blockIdx.x, b = blockIdx.y;
  const int row0 = rb * 64;
  const int tid = threadIdx.x, wave = tid >> 6, l = tid & 63;

  __shared__ __align__(16) unsigned short A[4 * 8192];  // 64 KB swizzled frag-order
  __shared__ float sred[16][64];
  __shared__ float sscore[64];

  // ---- stage: coalesced row-major fp32 load -> cvt -> swizzled ds_write ----
  {
    const int r = tid >> 4;       // 0..63
    const int j = tid & 15;
    const int grow = row0 + r;
    const float* srcrow = nullptr;
    if (grow < MM) srcrow = feat_mem + ((size_t)b * MM + grow) * DD;
    else if (grow == MM) srcrow = x + (size_t)b * LSEQ * DD;
    const int rt = r >> 4, lrow = r & 15;
#pragma unroll
    for (int it = 0; it < 8; ++it) {
      const int k0 = it * 64 + j * 4;
      const float4 v = srcrow ? *(const float4*)(srcrow + k0) : make_float4(0.f, 0.f, 0.f, 0.f);
      const int kc = k0 >> 7, kin = k0 & 127;
      const int ks = kin >> 5, lhi = (kin >> 3) & 3, ii = kin & 7;  // ii in {0,4}
      uint2 p;
      p.x = cvt_pk_bf16(v.x, v.y);
      p.y = cvt_pk_bf16(v.z, v.w);
      const int U = kc * 8192 + (ks * 4 + rt) * 512 + lhi * 128 +
                    ((lrow * 8) ^ (lhi << 3) ^ ((ks & 1) << 5)) + ii;
      *(uint2*)(A + U) = p;
    }
  }
  __syncthreads();

  // ---- MFMA: 16 ksg x (4 rt x 4 ct); lazy B loads (R6 shape, no dbuf) ------
  f32x4 acc[4][4];
#pragma unroll
  for (int i = 0; i < 4; ++i)
#pragma unroll
    for (int j2 = 0; j2 < 4; ++j2) acc[i][j2] = (f32x4){0.f, 0.f, 0.f, 0.f};

  const unsigned short* Bwave = Bc + ((size_t)(wave * 4) * 16) * 512 + l * 8;
  const int lanebase = l * 8 ^ ((l >> 4) << 3);
#pragma unroll 4
  for (int ksg = 0; ksg < 16; ++ksg) {
    const unsigned short* Ab =
        A + (ksg >> 2) * 8192 + (ksg & 3) * 2048 + (lanebase ^ ((ksg & 1) << 5));
    bf16x8 hiA[4];
#pragma unroll
    for (int rt = 0; rt < 4; ++rt) hiA[rt] = *(const bf16x8*)(Ab + rt * 512);
#pragma unroll
    for (int ct = 0; ct < 4; ++ct) {
      const bf16x8 bb = *(const bf16x8*)(Bwave + (size_t)(ct * 16 + ksg) * 512);
#pragma unroll
      for (int rt = 0; rt < 4; ++rt)
        acc[rt][ct] = __builtin_amdgcn_mfma_f32_16x16x32_bf16(hiA[rt], bb, acc[rt][ct], 0, 0, 0);
    }
  }

  // ---- epilogue: tanh(v+bv)*sig(u+bu)*Ww over wave's 32 cols ---------------
  float prow[4][4];
#pragma unroll
  for (int i = 0; i < 4; ++i)
#pragma unroll
    for (int j2 = 0; j2 < 4; ++j2) prow[i][j2] = 0.f;
#pragma unroll
  for (int gp = 0; gp < 2; ++gp) {
    const int col = (wave * 2 + gp) * 16 + (l & 15);
    const float bvc = bv[col], buc = bu[col], wwc = Ww[col];
#pragma unroll
    for (int rt = 0; rt < 4; ++rt)
#pragma unroll
      for (int rr = 0; rr < 4; ++rr) {
        const float vv = tanh_fast(acc[rt][2 * gp][rr] + bvc);
        const float uu = sig_fast(acc[rt][2 * gp + 1][rr] + buc);
        prow[rt][rr] = fmaf(vv * uu, wwc, prow[rt][rr]);
      }
  }
#pragma unroll
  for (int off = 1; off < 16; off <<= 1)
#pragma unroll
    for (int rt = 0; rt < 4; ++rt)
#pragma unroll
      for (int rr = 0; rr < 4; ++rr) prow[rt][rr] += __shfl_xor(prow[rt][rr], off, 64);

  if ((l & 15) == 0) {
#pragma unroll
    for (int rt = 0; rt < 4; ++rt)
#pragma unroll
      for (int rr = 0; rr < 4; ++rr) sred[wave][rt * 16 + (l >> 4) * 4 + rr] = prow[rt][rr];
  }
  __syncthreads();

  if (tid < 64) {
    float s = 0.f;
#pragma unroll
    for (int w = 0; w < 16; ++w) s += sred[w][tid];
    const int row = row0 + tid;
    if (row < MP1) logits[(size_t)b * MP1 + row] = s;   // raw logit (no bw)
    sscore[tid] = sig_fast(s + bw[0]);
  }
  __syncthreads();

  // ---- in-block z partial: zacc[d] += sum_r score[r] * A[r][d] (swizzled) --
  {
    const int d = tid & 511;
    const int rh = tid >> 9;  // 0,1 -> rows [0,32) / [32,64)
    const int kc = d >> 7, kin = d & 127;
    const int ks = kin >> 5, lhi = (kin >> 3) & 3, ii = kin & 7;
    const int ubase = kc * 8192 + ks * 2048 + lhi * 128 + ii;
    const int swz = (lhi << 3) ^ ((ks & 1) << 5);
    float zp = 0.f;
#pragma unroll
    for (int rr2 = 0; rr2 < 32; ++rr2) {
      const int r2 = rh * 32 + rr2;
      const int U = ubase + (r2 >> 4) * 512 + (((r2 & 15) * 8) ^ swz);
      zp = fmaf(sscore[r2], bf16_to_f(A[U]), zp);
    }
    atomicAdd(&zacc[(size_t)b * DD + d], zp);
  }
}

// ---- candidate selection: rows with cheap logit <= min + MARGIN ------------
__global__ __launch_bounds__(256) void k_cand(const float* __restrict__ logits,
                                              int* __restrict__ cand,
                                              int* __restrict__ cnt) {
  const int b = blockIdx.x, tid = threadIdx.x;
  __shared__ float sv[256];
  __shared__ int scnt;
  float m = INFINITY;
  for (int i = tid; i < MP1; i += 256) m = fminf(m, logits[(size_t)b * MP1 + i]);
  sv[tid] = m;
  __syncthreads();
  for (int s = 128; s >= 1; s >>= 1) {
    if (tid < s) sv[tid] = fminf(sv[tid], sv[tid + s]);
    __syncthreads();
  }
  const float minv = sv[0];
  if (tid == 0) scnt = 0;
  __syncthreads();
  for (int i = tid; i < MP1; i += 256) {
    if (logits[(size_t)b * MP1 + i] <= minv + MARGIN) {
      const int p = atomicAdd(&scnt, 1);
      if (p < CANDMAX) cand[b * CANDMAX + p] = i;
    }
  }
  __syncthreads();
  if (tid == 0) cnt[b] = (scnt < CANDMAX) ? scnt : CANDMAX;
}

// ---- exact fp32 logit partials for candidate rows (col-block parallel) -----
__global__ __launch_bounds__(256) void k_refine(
    const float* __restrict__ x, const float* __restrict__ feat_mem,
    const float* __restrict__ Wv, const float* __restrict__ bv,
    const float* __restrict__ Wu, const float* __restrict__ bu,
    const float* __restrict__ Ww,
    const int* __restrict__ cand, const int* __restrict__ cnt,
    float* __restrict__ candpart) {
  const int b = blockIdx.z, c = blockIdx.y, cb = blockIdx.x;
  if (c >= cnt[b]) return;
  const int row = cand[b * CANDMAX + c];
  const int tid = threadIdx.x;
  const int jl = tid & 63;
  const int ks = tid >> 6;
  const int col = cb * 64 + jl;
  __shared__ __align__(16) float sfeat[DD];
  __shared__ float sredv[4][64];
  __shared__ float sredu[4][64];
  const float* src = (row < MM) ? feat_mem + ((size_t)b * MM + row) * DD
                                : x + (size_t)b * LSEQ * DD;
  if (tid < 128) ((float4*)sfeat)[tid] = ((const float4*)src)[tid];
  __syncthreads();
  float v = 0.f, u = 0.f;
  const float* wvp = Wv + (size_t)(ks * 128) * DD + col;
  const float* wup = Wu + (size_t)(ks * 128) * DD + col;
#pragma unroll 8
  for (int k = 0; k < 128; ++k) {
    const float a = sfeat[ks * 128 + k];
    v = fmaf(a, wvp[(size_t)k * DD], v);
    u = fmaf(a, wup[(size_t)k * DD], u);
  }
  sredv[ks][jl] = v;
  sredu[ks][jl] = u;
  __syncthreads();
  if (tid < 64) {
    const float vv = (sredv[0][jl] + sredv[1][jl]) + (sredv[2][jl] + sredv[3][jl]);
    const float uu = (sredu[0][jl] + sredu[1][jl]) + (sredu[2][jl] + sredu[3][jl]);
    float g = tanhf(vv + bv[col]) * sig_prec(uu + bu[col]) * Ww[col];
#pragma unroll
    for (int off = 1; off < 64; off <<= 1) g += __shfl_xor(g, off, 64);
    if (jl == 0) candpart[((size_t)b * CANDMAX + c) * 8 + cb] = g;
  }
}

// ---- finalize: argmin over refined candidate logits + exact-rational argmax -
__global__ __launch_bounds__(256) void k_finalize2(
    const int* __restrict__ cand, const float* __restrict__ candpart,
    const int* __restrict__ cnt, const int* __restrict__ freq_mem,
    const int* __restrict__ min_mem, const float* __restrict__ zacc,
    float* __restrict__ out_z, float* __restrict__ out_freq,
    float* __restrict__ out_min, int* __restrict__ rm_attn) {
  const int b = blockIdx.x, tid = threadIdx.x;
  __shared__ float sv[256];
  __shared__ int si[256];
  __shared__ int sn[256], sd[256], sj[256];
  __shared__ int s_attn, s_rm;

  const int n = cnt[b];
  float v = INFINITY;
  int idx = MP1;
  if (tid < n) {
    const float* p = candpart + ((size_t)b * CANDMAX + tid) * 8;
    v = ((p[0] + p[1]) + (p[2] + p[3])) + ((p[4] + p[5]) + (p[6] + p[7]));
    idx = cand[b * CANDMAX + tid];
  }
  sv[tid] = v; si[tid] = idx;
  __syncthreads();
  for (int s = 128; s >= 1; s >>= 1) {
    if (tid < s) {
      const float v2 = sv[tid + s]; const int i2 = si[tid + s];
      if (v2 < sv[tid] || (v2 == sv[tid] && i2 < si[tid])) { sv[tid] = v2; si[tid] = i2; }
    }
    __syncthreads();
  }
  if (tid == 0) s_attn = si[0];
  __syncthreads();
  const int attn = s_attn;

  int bn = -1, bd = 1, bj = 0;
  for (int i = tid; i < MP1; i += 256) {
    int num, den;
    if (i < MM) {
      den = freq_mem[(size_t)b * MM + i] + 1;
      num = min_mem[(size_t)b * MM + i] + (i == attn ? 1 : 0);
      if (den <= 5) num = 0;
    } else { den = 1; num = 0; }
    if (num * bd > bn * den) { bn = num; bd = den; bj = i; }
  }
  sn[tid] = bn; sd[tid] = bd; sj[tid] = bj;
  __syncthreads();
  for (int s = 128; s >= 1; s >>= 1) {
    if (tid < s) {
      const int n2 = sn[tid + s], d2 = sd[tid + s], j2 = sj[tid + s];
      const int lft = n2 * sd[tid], rgt = sn[tid] * d2;
      if (lft > rgt || (lft == rgt && j2 < sj[tid])) { sn[tid] = n2; sd[tid] = d2; sj[tid] = j2; }
    }
    __syncthreads();
  }
  if (tid == 0) { s_rm = sj[0]; rm_attn[b * 2] = attn; rm_attn[b * 2 + 1] = sj[0]; }
  __syncthreads();
  const int rm = s_rm;

  for (int i = tid; i < MM; i += 256) {
    const int src = (i < rm) ? i : i + 1;
    int fv, mv;
    if (src < MM) {
      fv = freq_mem[(size_t)b * MM + src] + 1;
      mv = min_mem[(size_t)b * MM + src] + (src == attn ? 1 : 0);
    } else {
      fv = 1; mv = (attn == MM) ? 1 : 0;
    }
    out_freq[(size_t)b * MM + i] = (float)fv;
    out_min[(size_t)b * MM + i] = (float)mv;
  }
  for (int d = tid; d < DD; d += 256) out_z[(size_t)b * DD + d] = zacc[(size_t)b * DD + d];
}

// ---- feat_out gather (verified R1-R13) --------------------------------------
__global__ __launch_bounds__(256) void k_gather(
    const float* __restrict__ feat_mem, const float* __restrict__ x,
    const int* __restrict__ rm_attn, float* __restrict__ out_feat) {
  const int b = blockIdx.y;
  const int rm = rm_attn[b * 2 + 1];
  const int row = blockIdx.x * 4 + (threadIdx.x >> 6);
  const int lane = threadIdx.x & 63;
  const int src = (row < rm) ? row : row + 1;
  const float* sp = (src < MM) ? (feat_mem + ((size_t)b * MM + src) * DD)
                               : (x + (size_t)b * LSEQ * DD);
  float* dp = out_feat + ((size_t)b * MM + row) * DD;
  const float4 v0 = reinterpret_cast<const float4*>(sp)[lane];
  const float4 v1 = reinterpret_cast<const float4*>(sp)[lane + 64];
  reinterpret_cast<float4*>(dp)[lane] = v0;
  reinterpret_cast<float4*>(dp)[lane + 64] = v1;
}

extern "C" void kernel_launch(void* const* d_in, const int* in_sizes, int n_in,
                              void* d_out, int out_size, void* d_ws, size_t ws_size,
                              hipStream_t stream) {
  const float* x        = (const float*)d_in[0];
  const float* feat_mem = (const float*)d_in[1];
  const int*   freq_mem = (const int*)d_in[2];
  const int*   min_mem  = (const int*)d_in[3];
  const float* Wv       = (const float*)d_in[4];
  const float* bv       = (const float*)d_in[5];
  const float* Wu       = (const float*)d_in[6];
  const float* bu       = (const float*)d_in[7];
  const float* Ww       = (const float*)d_in[8];
  const float* bw       = (const float*)d_in[9];

  float* ws       = (float*)d_ws;
  float* logits   = ws;                                   // 65552
  float* zacc     = ws + NB * MP1;                        // 8192
  float* candpart = zacc + NB * DD;                       // 16384
  int*   cand     = (int*)(candpart + NB * CANDMAX * 8);  // 2048
  int*   cnt      = cand + NB * CANDMAX;                  // 16
  int*   rm_attn  = cnt + NB;                             // 32
  unsigned short* Bc = (unsigned short*)(rm_attn + 32);   // 1 MB

  float* out_z    = (float*)d_out;
  float* out_feat = out_z + NB * DD;
  float* out_freq = out_feat + (size_t)NB * MM * DD;
  float* out_min  = out_freq + (size_t)NB * MM;

  hipMemsetAsync(zacc, 0, NB * DD * sizeof(float), stream);
  hipMemsetAsync(cnt, 0, NB * sizeof(int), stream);

  k_packW<<<dim3(256), dim3(256), 0, stream>>>(Wv, Wu, Bc);
  k_scores<<<dim3(NRB, NB), dim3(1024), 0, stream>>>(x, feat_mem, Bc, bv, bu, Ww, bw,
                                                     logits, zacc);
  k_cand<<<dim3(NB), dim3(256), 0, stream>>>(logits, cand, cnt);
  k_refine<<<dim3(8, CANDMAX, NB), dim3(256), 0, stream>>>(x, feat_mem, Wv, bv, Wu, bu, Ww,
                                                           cand, cnt, candpart);
  k_finalize2<<<dim3(NB), dim3(256), 0, stream>>>(cand, candpart, cnt, freq_mem, min_mem, zacc,
                                                  out_z, out_freq, out_min, rm_attn);
  k_gather<<<dim3(MM / 4, NB), dim3(256), 0, stream>>>(feat_mem, x, rm_attn, out_feat);
}